// Round 1
// baseline (465.646 us; speedup 1.0000x reference)
//
#include <hip/hip_runtime.h>
#include <math.h>

// Problem constants (from reference): B=128, T=200, V=10, F=256.
constexpr int NV  = 10;
constexpr int NF  = 256;
constexpr int NC  = NV * NV;   // 100 cells per graph
constexpr int GPB = 4;         // graphs per block = 1 per wave (wave64)

// One wave per (b,t) graph: all graph math is wave-synchronous (no barriers).
// Within a wave, LDS write->read ordering is guaranteed by lockstep execution
// plus compiler-inserted lgkmcnt waits. In-place FW is safe intra-step: at
// step k, reads touch only row-k/col-k cells, which are never relaxed at
// step k (dist >= 0 => t >= dist for those cells).
//
// Phase order (v2): stage + sym + Di -> ONE barrier -> stream (dominant HBM
// traffic issues immediately) -> graph math in the memory shadow.
__global__ __launch_bounds__(256) void graph_emb_fused(
    const float* __restrict__ end_output,  // (BT, V, F)
    const float* __restrict__ S,           // (BT, V, V)
    const float* __restrict__ mul,         // (V, V)
    const float* __restrict__ bias,        // (V, V)
    const float* __restrict__ means,       // (1, V)
    const float* __restrict__ stds,        // (1, V)
    const float* __restrict__ emb_in,      // (F, F) rows 0..9 used
    const float* __restrict__ emb_out,     // (F, F)
    const float* __restrict__ emb3,        // (V, V)
    const float* __restrict__ emb4,        // (V, V)
    float* __restrict__ out_main,          // (BT, V, F)
    float* __restrict__ out_atten,         // (BT, V, V)
    int BT)
{
    __shared__ __attribute__((aligned(16))) float s_embsum[NV * NF];
    __shared__ float s_mul[NC], s_bias[NC], s_emb3[NC], s_emb4[NC];
    __shared__ float s_means[NV], s_stds[NV];
    __shared__ float s_dist[GPB][NC];
    __shared__ int   s_si[GPB][NC];
    __shared__ int   s_ei[GPB][NC];
    __shared__ int   s_Di[GPB][NV];   // flattened: chunk = g_local*NV + row

    const int tid   = threadIdx.x;
    const int wave  = tid >> 6;
    const int lane  = tid & 63;
    const int gbase = blockIdx.x * GPB;
    const int g     = gbase + wave;

    // ---- Table staging (block-wide) ----
    for (int idx = tid; idx < NV * NF; idx += 256)
        s_embsum[idx] = emb_in[idx] + emb_out[idx];
    if (tid < NC) {
        s_mul[tid]  = mul[tid];
        s_bias[tid] = bias[tid];
        s_emb3[tid] = emb3[tid];
        s_emb4[tid] = emb4[tid];
    }
    if (tid >= 128 && tid < 128 + NV) {
        s_means[tid - 128] = means[tid - 128];
        s_stds[tid - 128]  = stds[tid - 128];
    }

    const int c0 = lane;          // cells 0..63
    const int c1 = 64 + lane;     // cells 64..99 (lane < 36)
    const bool has1 = (lane < 36);
    const int i0 = c0 / NV, j0 = c0 % NV;
    const int i1 = c1 / NV, j1 = c1 % NV;

    // ---- Per-wave pre-barrier work: symmetrize + degree buckets ----
    if (g < BT) {
        const int g0 = g * NC;
        s_dist[wave][c0] = fminf(S[g0 + c0], S[g0 + j0 * NV + i0]);
        if (has1)
            s_dist[wave][c1] = fminf(S[g0 + c1], S[g0 + j1 * NV + i1]);

        // Degree buckets (lanes 0..9), read pre-FW dist (== sym)
        if (lane < NV) {
            float d = 0.f;
            #pragma unroll
            for (int i = 0; i < NV; ++i) d += s_dist[wave][i * NV + lane];
            int di = (int)d;   // d in [0,10): trunc == astype(int32)
            s_Di[wave][lane] = min(max(di, 0), NV - 1);
        }
    }

    // ---- Single barrier: publishes s_embsum + s_Di across waves ----
    __syncthreads();

    // ---- Streaming phase FIRST: dominant HBM traffic issues now ----
    {
        const size_t slab  = (size_t)gbase * (NV * NF);
        const float4* end4 = reinterpret_cast<const float4*>(end_output + slab);
        float4*       out4 = reinterpret_cast<float4*>(out_main + slab);
        const float4* es4  = reinterpret_cast<const float4*>(s_embsum);
        const int*    sdi  = &s_Di[0][0];   // 40 entries == chunk-indexed

        if (gbase + GPB <= BT) {
            // Full block (always true for BT=25600): 40 chunks of 64 float4,
            // chunk == (g_local, V-row). No division, fixed trip count ->
            // 10 independent dwordx4 loads in flight per lane.
            #pragma unroll
            for (int it = 0; it < NV; ++it) {
                const int chunk = it * GPB + wave;
                const int u     = (chunk << 6) + lane;
                float4 e = end4[u];
                float4 s = es4[sdi[chunk] * (NF / 4) + lane];
                e.x += s.x; e.y += s.y; e.z += s.z; e.w += s.w;
                out4[u] = e;
            }
        } else {
            const int ng    = BT - gbase;           // partial tail block
            const int items = ng * (NV * NF / 4);
            for (int u = tid; u < items; u += 256) {
                int gg = u / 640, rem = u - gg * 640;
                int row = rem >> 6, f4 = rem & 63;
                float4 e = end4[u];
                float4 s = es4[sdi[gg * NV + row] * (NF / 4) + f4];
                e.x += s.x; e.y += s.y; e.z += s.z; e.w += s.w;
                out4[u] = e;
            }
        }
    }

    // ---- Graph math in the memory shadow (wave-synchronous, no barriers) ----
    if (g < BT) {
        const int g0 = g * NC;

        // GaussianLayer edge features -> registers (uses pre-FW dist)
        const float A = sqrtf(2.0f * 3.14159f);
        float ef0 = 0.f, ef1 = 0.f, sp0 = 0.f, sp1 = 0.f;
        {
            float acc = 0.f;
            #pragma unroll
            for (int j = 0; j < NV; ++j)
                acc += s_dist[wave][i0 * NV + j] * s_mul[j * NV + j0];
            float x = acc + s_bias[c0];
            float z = (x - s_means[j0]) / s_stds[j0];
            float tmp = expf(-0.5f * z * z) / (A * s_stds[j0]);
            float sg = 1.0f / (1.0f + expf(-tmp));
            ef0 = tanhf(sg);
        }
        if (has1) {
            float acc = 0.f;
            #pragma unroll
            for (int j = 0; j < NV; ++j)
                acc += s_dist[wave][i1 * NV + j] * s_mul[j * NV + j1];
            float x = acc + s_bias[c1];
            float z = (x - s_means[j1]) / s_stds[j1];
            float tmp = expf(-0.5f * z * z) / (A * s_stds[j1]);
            float sg = 1.0f / (1.0f + expf(-tmp));
            ef1 = tanhf(sg);
        }

        // Floyd-Warshall, wave-synchronous, in-place
        #pragma unroll
        for (int k = 0; k < NV; ++k) {
            float t0 = s_dist[wave][i0 * NV + k] + s_dist[wave][k * NV + j0];
            if (t0 < s_dist[wave][c0]) { s_dist[wave][c0] = t0; sp0 += ef0; }
            if (has1) {
                float t1 = s_dist[wave][i1 * NV + k] + s_dist[wave][k * NV + j1];
                if (t1 < s_dist[wave][c1]) { s_dist[wave][c1] = t1; sp1 += ef1; }
            }
        }

        // Integer buckets
        {
            int si = (int)s_dist[wave][c0];
            int ei = (int)sp0;
            s_si[wave][c0] = min(max(si, 0), NV - 1);
            s_ei[wave][c0] = min(max(ei, 0), NV - 1);
        }
        if (has1) {
            int si = (int)s_dist[wave][c1];
            int ei = (int)sp1;
            s_si[wave][c1] = min(max(si, 0), NV - 1);
            s_ei[wave][c1] = min(max(ei, 0), NV - 1);
        }

        // atten_bias = sum_j emb3[Si[i,j]] + emb4[Ei[i,j]]  (per cell (i,cc))
        {
            float acc3 = 0.f, acc4 = 0.f;
            #pragma unroll
            for (int j = 0; j < NV; ++j) {
                acc3 += s_emb3[s_si[wave][i0 * NV + j] * NV + j0];
                acc4 += s_emb4[s_ei[wave][i0 * NV + j] * NV + j0];
            }
            out_atten[g0 + c0] = acc4 + acc3;
        }
        if (has1) {
            float acc3 = 0.f, acc4 = 0.f;
            #pragma unroll
            for (int j = 0; j < NV; ++j) {
                acc3 += s_emb3[s_si[wave][i1 * NV + j] * NV + j1];
                acc4 += s_emb4[s_ei[wave][i1 * NV + j] * NV + j1];
            }
            out_atten[g0 + c1] = acc4 + acc3;
        }
    }
}

extern "C" void kernel_launch(void* const* d_in, const int* in_sizes, int n_in,
                              void* d_out, int out_size, void* d_ws, size_t ws_size,
                              hipStream_t stream) {
    const float* end_output = (const float*)d_in[0];
    const float* S          = (const float*)d_in[1];
    const float* mul        = (const float*)d_in[2];
    const float* bias       = (const float*)d_in[3];
    const float* means      = (const float*)d_in[4];
    const float* stds       = (const float*)d_in[5];
    const float* emb_in     = (const float*)d_in[6];
    const float* emb_out    = (const float*)d_in[7];
    const float* emb3       = (const float*)d_in[8];
    const float* emb4       = (const float*)d_in[9];

    float* out_main  = (float*)d_out;
    float* out_atten = out_main + (size_t)in_sizes[0];

    const int BT = in_sizes[1] / (NV * NV);         // 25,600
    const int nblocks = (BT + GPB - 1) / GPB;       // 6,400

    graph_emb_fused<<<nblocks, 256, 0, stream>>>(
        end_output, S, mul, bias, means, stds,
        emb_in, emb_out, emb3, emb4, out_main, out_atten, BT);
}

// Round 3
// 458.465 us; speedup vs baseline: 1.0157x; 1.0157x over previous
//
#include <hip/hip_runtime.h>
#include <math.h>

// Problem constants (from reference): B=128, T=200, V=10, F=256.
constexpr int NV  = 10;
constexpr int NF  = 256;
constexpr int NC  = NV * NV;   // 100 cells per graph
constexpr int GPB = 4;         // graphs per block = 1 per wave (wave64)

// Native clang vector: __builtin_nontemporal_* requires ext_vector_type,
// not HIP's float4 class.
typedef float v4f __attribute__((ext_vector_type(4)));

// One wave per (b,t) graph: all graph math is wave-synchronous (no barriers).
// Within a wave, LDS write->read ordering is guaranteed by lockstep execution
// plus compiler-inserted lgkmcnt waits. In-place FW is safe intra-step: at
// step k, reads touch only row-k/col-k cells, which are never relaxed at
// step k (dist >= 0 => t >= dist for those cells).
//
// v4 = v3 with ext_vector_type for the nontemporal builtins:
// the 524 MB end_output->out_main stream is single-touch; mark it
// non-temporal (gfx950 'nt' cache flag) so it doesn't write-allocate /
// thrash L2 against itself.
__global__ __launch_bounds__(256) void graph_emb_fused(
    const float* __restrict__ end_output,  // (BT, V, F)
    const float* __restrict__ S,           // (BT, V, V)
    const float* __restrict__ mul,         // (V, V)
    const float* __restrict__ bias,        // (V, V)
    const float* __restrict__ means,       // (1, V)
    const float* __restrict__ stds,        // (1, V)
    const float* __restrict__ emb_in,      // (F, F) rows 0..9 used
    const float* __restrict__ emb_out,     // (F, F)
    const float* __restrict__ emb3,        // (V, V)
    const float* __restrict__ emb4,        // (V, V)
    float* __restrict__ out_main,          // (BT, V, F)
    float* __restrict__ out_atten,         // (BT, V, V)
    int BT)
{
    __shared__ __attribute__((aligned(16))) float s_embsum[NV * NF];
    __shared__ float s_mul[NC], s_bias[NC], s_emb3[NC], s_emb4[NC];
    __shared__ float s_means[NV], s_stds[NV];
    __shared__ float s_dist[GPB][NC];
    __shared__ int   s_si[GPB][NC];
    __shared__ int   s_ei[GPB][NC];
    __shared__ int   s_Di[GPB][NV];   // flattened: chunk = g_local*NV + row

    const int tid   = threadIdx.x;
    const int wave  = tid >> 6;
    const int lane  = tid & 63;
    const int gbase = blockIdx.x * GPB;
    const int g     = gbase + wave;

    // ---- Table staging (block-wide) ----
    for (int idx = tid; idx < NV * NF; idx += 256)
        s_embsum[idx] = emb_in[idx] + emb_out[idx];
    if (tid < NC) {
        s_mul[tid]  = mul[tid];
        s_bias[tid] = bias[tid];
        s_emb3[tid] = emb3[tid];
        s_emb4[tid] = emb4[tid];
    }
    if (tid >= 128 && tid < 128 + NV) {
        s_means[tid - 128] = means[tid - 128];
        s_stds[tid - 128]  = stds[tid - 128];
    }

    const int c0 = lane;          // cells 0..63
    const int c1 = 64 + lane;     // cells 64..99 (lane < 36)
    const bool has1 = (lane < 36);
    const int i0 = c0 / NV, j0 = c0 % NV;
    const int i1 = c1 / NV, j1 = c1 % NV;

    // ---- Per-wave pre-barrier work: symmetrize + degree buckets ----
    if (g < BT) {
        const int g0 = g * NC;
        s_dist[wave][c0] = fminf(S[g0 + c0], S[g0 + j0 * NV + i0]);
        if (has1)
            s_dist[wave][c1] = fminf(S[g0 + c1], S[g0 + j1 * NV + i1]);

        // Degree buckets (lanes 0..9), read pre-FW dist (== sym)
        if (lane < NV) {
            float d = 0.f;
            #pragma unroll
            for (int i = 0; i < NV; ++i) d += s_dist[wave][i * NV + lane];
            int di = (int)d;   // d in [0,10): trunc == astype(int32)
            s_Di[wave][lane] = min(max(di, 0), NV - 1);
        }
    }

    // ---- Single barrier: publishes s_embsum + s_Di across waves ----
    __syncthreads();

    // ---- Streaming phase: single-touch, non-temporal ----
    {
        const size_t slab = (size_t)gbase * (NV * NF);
        const v4f* end4 = reinterpret_cast<const v4f*>(end_output + slab);
        v4f*       out4 = reinterpret_cast<v4f*>(out_main + slab);
        const v4f* es4  = reinterpret_cast<const v4f*>(s_embsum);
        const int* sdi  = &s_Di[0][0];   // 40 entries == chunk-indexed

        if (gbase + GPB <= BT) {
            // Full block (always true for BT=25600): 40 chunks of 64 float4,
            // chunk == (g_local, V-row). Fixed trip count, no division ->
            // 10 independent nt dwordx4 loads in flight per lane.
            #pragma unroll
            for (int it = 0; it < NV; ++it) {
                const int chunk = it * GPB + wave;
                const int u     = (chunk << 6) + lane;
                v4f e = __builtin_nontemporal_load(end4 + u);
                v4f s = es4[sdi[chunk] * (NF / 4) + lane];
                e += s;
                __builtin_nontemporal_store(e, out4 + u);
            }
        } else {
            const int ng    = BT - gbase;           // partial tail block
            const int items = ng * (NV * NF / 4);
            for (int u = tid; u < items; u += 256) {
                int gg = u / 640, rem = u - gg * 640;
                int row = rem >> 6, f4 = rem & 63;
                v4f e = __builtin_nontemporal_load(end4 + u);
                v4f s = es4[sdi[gg * NV + row] * (NF / 4) + f4];
                e += s;
                __builtin_nontemporal_store(e, out4 + u);
            }
        }
    }

    // ---- Graph math in the memory shadow (wave-synchronous, no barriers) ----
    if (g < BT) {
        const int g0 = g * NC;

        // GaussianLayer edge features -> registers (uses pre-FW dist)
        const float A = sqrtf(2.0f * 3.14159f);
        float ef0 = 0.f, ef1 = 0.f, sp0 = 0.f, sp1 = 0.f;
        {
            float acc = 0.f;
            #pragma unroll
            for (int j = 0; j < NV; ++j)
                acc += s_dist[wave][i0 * NV + j] * s_mul[j * NV + j0];
            float x = acc + s_bias[c0];
            float z = (x - s_means[j0]) / s_stds[j0];
            float tmp = expf(-0.5f * z * z) / (A * s_stds[j0]);
            float sg = 1.0f / (1.0f + expf(-tmp));
            ef0 = tanhf(sg);
        }
        if (has1) {
            float acc = 0.f;
            #pragma unroll
            for (int j = 0; j < NV; ++j)
                acc += s_dist[wave][i1 * NV + j] * s_mul[j * NV + j1];
            float x = acc + s_bias[c1];
            float z = (x - s_means[j1]) / s_stds[j1];
            float tmp = expf(-0.5f * z * z) / (A * s_stds[j1]);
            float sg = 1.0f / (1.0f + expf(-tmp));
            ef1 = tanhf(sg);
        }

        // Floyd-Warshall, wave-synchronous, in-place
        #pragma unroll
        for (int k = 0; k < NV; ++k) {
            float t0 = s_dist[wave][i0 * NV + k] + s_dist[wave][k * NV + j0];
            if (t0 < s_dist[wave][c0]) { s_dist[wave][c0] = t0; sp0 += ef0; }
            if (has1) {
                float t1 = s_dist[wave][i1 * NV + k] + s_dist[wave][k * NV + j1];
                if (t1 < s_dist[wave][c1]) { s_dist[wave][c1] = t1; sp1 += ef1; }
            }
        }

        // Integer buckets
        {
            int si = (int)s_dist[wave][c0];
            int ei = (int)sp0;
            s_si[wave][c0] = min(max(si, 0), NV - 1);
            s_ei[wave][c0] = min(max(ei, 0), NV - 1);
        }
        if (has1) {
            int si = (int)s_dist[wave][c1];
            int ei = (int)sp1;
            s_si[wave][c1] = min(max(si, 0), NV - 1);
            s_ei[wave][c1] = min(max(ei, 0), NV - 1);
        }

        // atten_bias = sum_j emb3[Si[i,j]] + emb4[Ei[i,j]]  (per cell (i,cc))
        {
            float acc3 = 0.f, acc4 = 0.f;
            #pragma unroll
            for (int j = 0; j < NV; ++j) {
                acc3 += s_emb3[s_si[wave][i0 * NV + j] * NV + j0];
                acc4 += s_emb4[s_ei[wave][i0 * NV + j] * NV + j0];
            }
            __builtin_nontemporal_store(acc4 + acc3, out_atten + g0 + c0);
        }
        if (has1) {
            float acc3 = 0.f, acc4 = 0.f;
            #pragma unroll
            for (int j = 0; j < NV; ++j) {
                acc3 += s_emb3[s_si[wave][i1 * NV + j] * NV + j1];
                acc4 += s_emb4[s_ei[wave][i1 * NV + j] * NV + j1];
            }
            __builtin_nontemporal_store(acc4 + acc3, out_atten + g0 + c1);
        }
    }
}

extern "C" void kernel_launch(void* const* d_in, const int* in_sizes, int n_in,
                              void* d_out, int out_size, void* d_ws, size_t ws_size,
                              hipStream_t stream) {
    const float* end_output = (const float*)d_in[0];
    const float* S          = (const float*)d_in[1];
    const float* mul        = (const float*)d_in[2];
    const float* bias       = (const float*)d_in[3];
    const float* means      = (const float*)d_in[4];
    const float* stds       = (const float*)d_in[5];
    const float* emb_in     = (const float*)d_in[6];
    const float* emb_out    = (const float*)d_in[7];
    const float* emb3       = (const float*)d_in[8];
    const float* emb4       = (const float*)d_in[9];

    float* out_main  = (float*)d_out;
    float* out_atten = out_main + (size_t)in_sizes[0];

    const int BT = in_sizes[1] / (NV * NV);         // 25,600
    const int nblocks = (BT + GPB - 1) / GPB;       // 6,400

    graph_emb_fused<<<nblocks, 256, 0, stream>>>(
        end_output, S, mul, bias, means, stds,
        emb_in, emb_out, emb3, emb4, out_main, out_atten, BT);
}